// Round 2
// baseline (3677.036 us; speedup 1.0000x reference)
//
#include <hip/hip_runtime.h>

// LanguageModel: embed -> 2x LSTM(1024) -> proj(32000) -> log_softmax
// B=32, S=128, HID=1024, VOC=32000.  Rows m = b*S + s (4096 rows).

#define SEQ   128
#define NBAT  32
#define HID   1024
#define VOC   32000

typedef __attribute__((ext_vector_type(4))) float        f32x4;
typedef __attribute__((ext_vector_type(4))) unsigned int u32x4;
typedef __attribute__((ext_vector_type(2))) unsigned int u32x2;

__device__ __forceinline__ unsigned short f2bf(float f) {
    unsigned u = __builtin_bit_cast(unsigned, f);
    u += 0x7fffu + ((u >> 16) & 1u);          // RNE
    return (unsigned short)(u >> 16);
}
__device__ __forceinline__ unsigned pk2(float a, float b) {
    return (unsigned)f2bf(a) | ((unsigned)f2bf(b) << 16);
}
// inline-asm MFMA: avoids builtin-signature ambiguity (short8 vs __bf16x8).
// A/B fragments need only a CONSISTENT (lane,elem)->k mapping (any shared
// k-permutation cancels in the contraction); C/D layout is the m89-verified
// col=lane&15, row=(lane>>4)*4+reg.
__device__ __forceinline__ void mfma16(f32x4& d, u32x4 a, u32x4 b) {
    asm("v_mfma_f32_16x16x32_bf16 %0, %1, %2, %0" : "+v"(d) : "v"(a), "v"(b));
}
// inline-asm MFMA is opaque to the hazard recognizer: pin manual s_nops
// before any VALU/ds read of the accumulators.
__device__ __forceinline__ void mfma_fence() {
    __builtin_amdgcn_sched_barrier(0);
    asm volatile("s_nop 7\ns_nop 7\ns_nop 7");
    __builtin_amdgcn_sched_barrier(0);
}

// ---------------- f32 -> bf16 bulk cast ----------------
__global__ void cast_bf16_k(const float* __restrict__ in,
                            unsigned short* __restrict__ out, int n4) {
    int i = blockIdx.x * blockDim.x + threadIdx.x;
    int stride = gridDim.x * blockDim.x;
    for (; i < n4; i += stride) {
        f32x4 v = ((const f32x4*)in)[i];
        u32x2 p = { pk2(v.x, v.y), pk2(v.z, v.w) };
        ((u32x2*)out)[i] = p;
    }
}

// ---------------- embedding gather (f32 -> bf16) ----------------
__global__ void gather_k(const int* __restrict__ tok, const float* __restrict__ emb,
                         unsigned short* __restrict__ xe) {
    int row = blockIdx.x;                       // b*S+s
    int t   = tok[row];
    const f32x4* src = (const f32x4*)(emb + (size_t)t * HID);
    u32x2*       dst = (u32x2*)(xe + (size_t)row * HID);
    int i = threadIdx.x;                        // 256 threads, 256 f32x4/row
    f32x4 v = src[i];
    u32x2 p = { pk2(v.x, v.y), pk2(v.z, v.w) };
    dst[i] = p;
}

// ---------------- 128x128-tile MFMA GEMM: C = A[M,1024] @ B[N,1024]^T + bias ----------------
// A bf16; B bf16 (BF32=false) or f32 converted during staging (BF32=true).
// LDS 16B-chunk XOR swizzle (chunk ^ (row&7)) -> conflict-free ds_read_b128.
// blockIdx.x -> M-tile (fast-moving) so co-scheduled blocks share one B panel
// (critical for the 131MB W_out: B is read ~once from HBM, A streams from L3).
template<bool BF32>
__global__ __launch_bounds__(256, 2) void gemm_k(
    const unsigned short* __restrict__ A, const void* __restrict__ Bsrc,
    const float* __restrict__ bias1, const float* __restrict__ bias2,
    float* __restrict__ C, int N)
{
    __shared__ u32x4 As[128][8];
    __shared__ u32x4 Bs[128][8];
    const int tid  = threadIdx.x;
    const int lane = tid & 63, wid = tid >> 6;
    const int wm = (wid >> 1) * 64, wn = (wid & 1) * 64;
    const int m0 = blockIdx.x * 128, n0 = blockIdx.y * 128;
    const int r = tid >> 1, half = tid & 1;     // staging: 2 threads per tile-row
    f32x4 acc[4][4] = {};

    const unsigned short* Ar = A + (size_t)(m0 + r) * HID + half * 32;
    for (int kt = 0; kt < HID / 64; ++kt) {
        const int k0 = kt * 64;
        {
            const u32x4* s = (const u32x4*)(Ar + k0);
            #pragma unroll
            for (int c = 0; c < 4; ++c)
                As[r][(half * 4 + c) ^ (r & 7)] = s[c];
        }
        if constexpr (!BF32) {
            const u32x4* s = (const u32x4*)((const unsigned short*)Bsrc +
                              (size_t)(n0 + r) * HID + half * 32 + k0);
            #pragma unroll
            for (int c = 0; c < 4; ++c)
                Bs[r][(half * 4 + c) ^ (r & 7)] = s[c];
        } else {
            const f32x4* s = (const f32x4*)((const float*)Bsrc +
                              (size_t)(n0 + r) * HID + half * 32 + k0);
            #pragma unroll
            for (int c = 0; c < 4; ++c) {
                f32x4 v0 = s[2 * c], v1 = s[2 * c + 1];
                u32x4 p = { pk2(v0.x, v0.y), pk2(v0.z, v0.w),
                            pk2(v1.x, v1.y), pk2(v1.z, v1.w) };
                Bs[r][(half * 4 + c) ^ (r & 7)] = p;
            }
        }
        __syncthreads();
        #pragma unroll
        for (int h = 0; h < 2; ++h) {
            u32x4 af[4], bfr[4];
            #pragma unroll
            for (int i = 0; i < 4; ++i) {
                int ra = wm + i * 16 + (lane & 15);
                af[i]  = As[ra][(h * 4 + (lane >> 4)) ^ (ra & 7)];
                int rb = wn + i * 16 + (lane & 15);
                bfr[i] = Bs[rb][(h * 4 + (lane >> 4)) ^ (rb & 7)];
            }
            #pragma unroll
            for (int i = 0; i < 4; ++i)
                #pragma unroll
                for (int j = 0; j < 4; ++j)
                    mfma16(acc[i][j], af[i], bfr[j]);
        }
        __syncthreads();
    }
    mfma_fence();
    #pragma unroll
    for (int j = 0; j < 4; ++j) {
        int col = n0 + wn + j * 16 + (lane & 15);
        float bv = 0.f;
        if (bias1) bv += bias1[col];
        if (bias2) bv += bias2[col];
        #pragma unroll
        for (int i = 0; i < 4; ++i) {
            int mrow = m0 + wm + i * 16 + (lane >> 4) * 4;
            #pragma unroll
            for (int q = 0; q < 4; ++q)
                C[(size_t)(mrow + q) * N + col] = acc[i][j][q] + bv;
        }
    }
}

// ---------------- fused LSTM step: gates = X[:,t] + h_{t-1} @ Whh^T ; cell ----------------
// 64 blocks; block owns 16 hidden units (wave w = gate w). h staged in LDS
// (XOR-swizzled), Whh rows streamed from L2 (per-block slice is L2-resident).
__global__ __launch_bounds__(256, 2) void lstm_k(
    const float* __restrict__ X, const unsigned short* __restrict__ Whh,
    unsigned short* __restrict__ hseq, float* __restrict__ cst, int t)
{
    __shared__ u32x4 hl[32][128];               // 32 batches x 1024 bf16 = 64KB
    __shared__ float gl[4][32][16];             // gate, batch, unit
    const int tid  = threadIdx.x;
    const int lane = tid & 63, wid = tid >> 6;
    const int u0 = blockIdx.x * 16;
    f32x4 acc0 = {}, acc1 = {};

    if (t > 0) {
        const int b = tid >> 3;
        const u32x4* src = (const u32x4*)(hseq + (size_t)(b * SEQ + t - 1) * HID);
        #pragma unroll
        for (int q = 0; q < 16; ++q) {
            int c = (tid & 7) + q * 8;
            hl[b][c ^ (b & 7)] = src[c];
        }
        __syncthreads();
        const unsigned short* Wr = Whh + (size_t)(wid * HID + u0 + (lane & 15)) * HID
                                       + (lane >> 4) * 8;
        #pragma unroll 8
        for (int ks = 0; ks < 32; ++ks) {
            u32x4 bf = *(const u32x4*)(Wr + ks * 32);
            u32x4 a0 = hl[lane & 15][(ks * 4 + (lane >> 4)) ^ (lane & 7)];
            u32x4 a1 = hl[16 + (lane & 15)][(ks * 4 + (lane >> 4)) ^ (lane & 7)];
            mfma16(acc0, a0, bf);
            mfma16(acc1, a1, bf);
        }
    }
    mfma_fence();
    #pragma unroll
    for (int q = 0; q < 4; ++q) {
        gl[wid][(lane >> 4) * 4 + q][lane & 15]      = acc0[q];
        gl[wid][16 + (lane >> 4) * 4 + q][lane & 15] = acc1[q];
    }
    __syncthreads();
    #pragma unroll
    for (int p = tid; p < 512; p += 256) {      // 32 batches x 16 units
        const int b = p >> 4, u = p & 15;
        const float* Xr = X + (size_t)(b * SEQ + t) * (4 * HID) + u0 + u;
        float ig = gl[0][b][u] + Xr[0];
        float fg = gl[1][b][u] + Xr[HID];
        float gg = gl[2][b][u] + Xr[2 * HID];
        float og = gl[3][b][u] + Xr[3 * HID];
        float cp = (t == 0) ? 0.f : cst[b * HID + u0 + u];
        float si = 1.f / (1.f + __expf(-ig));
        float sf = 1.f / (1.f + __expf(-fg));
        float so = 1.f / (1.f + __expf(-og));
        float tg = tanhf(gg);
        float cn = sf * cp + si * tg;
        float hn = so * tanhf(cn);
        cst[b * HID + u0 + u] = cn;
        hseq[(size_t)(b * SEQ + t) * HID + u0 + u] = f2bf(hn);
    }
}

// ---------------- in-place log_softmax per row (online max/sum, then subtract) ----------------
__global__ __launch_bounds__(256) void lsm_k(float* __restrict__ out) {
    const int tid = threadIdx.x;
    float* p = out + (size_t)blockIdx.x * VOC;
    float m = -1e30f, s = 0.f;
    for (int i = tid; i < VOC / 4; i += 256) {
        f32x4 v = ((const f32x4*)p)[i];
        float vm = fmaxf(fmaxf(v.x, v.y), fmaxf(v.z, v.w));
        if (vm > m) { s *= __expf(m - vm); m = vm; }
        s += __expf(v.x - m) + __expf(v.y - m) + __expf(v.z - m) + __expf(v.w - m);
    }
    #pragma unroll
    for (int o = 32; o; o >>= 1) {
        float om = __shfl_xor(m, o), os = __shfl_xor(s, o);
        float M = fmaxf(m, om);
        s = s * __expf(m - M) + os * __expf(om - M);
        m = M;
    }
    __shared__ float rm[4], rs[4];
    if ((tid & 63) == 0) { rm[tid >> 6] = m; rs[tid >> 6] = s; }
    __syncthreads();
    float M = fmaxf(fmaxf(rm[0], rm[1]), fmaxf(rm[2], rm[3]));
    float S = rs[0] * __expf(rm[0] - M) + rs[1] * __expf(rm[1] - M)
            + rs[2] * __expf(rm[2] - M) + rs[3] * __expf(rm[3] - M);
    float lse = M + logf(S);
    for (int i = tid; i < VOC / 4; i += 256) {
        f32x4 v = ((const f32x4*)p)[i];
        v.x -= lse; v.y -= lse; v.z -= lse; v.w -= lse;
        ((f32x4*)p)[i] = v;
    }
}

extern "C" void kernel_launch(void* const* d_in, const int* in_sizes, int n_in,
                              void* d_out, int out_size, void* d_ws, size_t ws_size,
                              hipStream_t stream)
{
    (void)in_sizes; (void)n_in; (void)out_size; (void)ws_size;
    const int*   tok  = (const int*)d_in[0];
    const float* emb  = (const float*)d_in[1];
    const float* Wih1 = (const float*)d_in[2];
    const float* Whh1 = (const float*)d_in[3];
    const float* bih1 = (const float*)d_in[4];
    const float* bhh1 = (const float*)d_in[5];
    const float* Wih2 = (const float*)d_in[6];
    const float* Whh2 = (const float*)d_in[7];
    const float* bih2 = (const float*)d_in[8];
    const float* bhh2 = (const float*)d_in[9];
    const float* Wout = (const float*)d_in[10];
    const float* bout = (const float*)d_in[11];
    float* out = (float*)d_out;
    char*  ws  = (char*)d_ws;

    // ws layout (~57 MB): bf16 weight copies + bf16 h-sequences + c-states.
    unsigned short* Wih1b = (unsigned short*)(ws + (0ull  << 20));
    unsigned short* Whh1b = (unsigned short*)(ws + (8ull  << 20));
    unsigned short* Wih2b = (unsigned short*)(ws + (16ull << 20));
    unsigned short* Whh2b = (unsigned short*)(ws + (24ull << 20));
    unsigned short* Xemb  = (unsigned short*)(ws + (32ull << 20));
    unsigned short* h1s   = (unsigned short*)(ws + (40ull << 20));
    unsigned short* h2s   = (unsigned short*)(ws + (48ull << 20));
    float* c1 = (float*)(ws + (56ull << 20));
    float* c2 = (float*)(ws + (56ull << 20) + (1ull << 19));
    // X1/X2 (64MB each, f32 gate pre-activations) live in d_out; the final
    // projection overwrites the whole 524MB region afterwards.
    float* X1 = out;
    float* X2 = out + (16ull << 20);

    const int n4w = (4 * HID * HID) / 4;
    cast_bf16_k<<<1024, 256, 0, stream>>>(Wih1, Wih1b, n4w);
    cast_bf16_k<<<1024, 256, 0, stream>>>(Whh1, Whh1b, n4w);
    cast_bf16_k<<<1024, 256, 0, stream>>>(Wih2, Wih2b, n4w);
    cast_bf16_k<<<1024, 256, 0, stream>>>(Whh2, Whh2b, n4w);
    gather_k<<<NBAT * SEQ, 256, 0, stream>>>(tok, emb, Xemb);

    // layer-1 input projection for all timesteps at once
    gemm_k<false><<<dim3(32, 32), 256, 0, stream>>>(Xemb, Wih1b, bih1, bhh1, X1, 4 * HID);
    for (int t = 0; t < SEQ; ++t)
        lstm_k<<<64, 256, 0, stream>>>(X1, Whh1b, h1s, c1, t);

    // layer-2 input projection (batched over t), then its recurrence
    gemm_k<false><<<dim3(32, 32), 256, 0, stream>>>(h1s, Wih2b, bih2, bhh2, X2, 4 * HID);
    for (int t = 0; t < SEQ; ++t)
        lstm_k<<<64, 256, 0, stream>>>(X2, Whh2b, h2s, c2, t);

    // output projection + log_softmax
    gemm_k<true><<<dim3(32, VOC / 128), 256, 0, stream>>>(h2s, Wout, bout, nullptr, out, VOC);
    lsm_k<<<NBAT * SEQ, 256, 0, stream>>>(out);
}